// Round 1
// 365.266 us; speedup vs baseline: 1.0001x; 1.0001x over previous
//
#include <hip/hip_runtime.h>
#include <hip/hip_bf16.h>

// Problem constants
#define B_SZ  64
#define CIN   512
#define T_IN  2048
#define COUT  512
#define KW_   5
#define TOUT  2044

// Main-kernel tile config: block 128(co) x 256(t), BK=32.
// 4 waves, each owning a 128(co) x 64(t) sub-tile (8x4 fragments of 16x16):
// LDS reads per iter per wave = 5kw*(8A+4B)=60 for 160 MFMA.
// LDS rows are 64B (32 bf16) = 4 chunks of 16B. Fragment reads (16 lanes,
// fixed chunk, 16 consecutive rows) hit only 2/8 bank-quads -> 8-way
// conflict (measured 3.15e7 extra cycles). Fix: XOR chunk swizzle
// chunk' = chunk ^ ((row>>1)&3), applied on BOTH the global_load_lds
// SOURCE address (LDS dest must stay linear) and the ds_read address.
#define BM    128
#define BN2   256
#define BK    32

typedef __attribute__((ext_vector_type(8))) short   short8;
typedef __attribute__((ext_vector_type(4))) float   floatx4;

__device__ __forceinline__ unsigned short f2bf(float f) {
    unsigned int u = __builtin_bit_cast(unsigned int, f);
    u += 0x7fffu + ((u >> 16) & 1u);   // RNE
    return (unsigned short)(u >> 16);
}

__device__ __forceinline__ void gl_lds16(const void* g, void* l) {
    __builtin_amdgcn_global_load_lds(
        (const __attribute__((address_space(1))) unsigned int*)g,
        (__attribute__((address_space(3))) unsigned int*)l, 16, 0, 0);
}

// ---------------- pre-kernel 1: W fp32 [co][ci][kw] -> bf16 [kw][co][ci] ----
__global__ __launch_bounds__(256)
void wconv_kernel(const float* __restrict__ w, unsigned short* __restrict__ wbf) {
    int i = blockIdx.x * 256 + threadIdx.x;
    if (i < COUT * CIN * KW_) {
        int kw = i % KW_;
        int r  = i / KW_;
        int ci = r % CIN;
        int co = r / CIN;
        wbf[((size_t)kw * COUT + co) * CIN + ci] = f2bf(w[i]);
    }
}

// ---------------- pre-kernel 2: X fp32 [b][ci][t] -> bf16 [b][t][ci] --------
__global__ __launch_bounds__(256)
void xtrans_kernel(const float* __restrict__ x, unsigned short* __restrict__ xbf) {
    __shared__ float tile[64][68];
    const int t0  = blockIdx.x * 64;
    const int ci0 = blockIdx.y * 64;
    const int b   = blockIdx.z;
    const int tid = threadIdx.x;

    const float* xb = x + ((size_t)b * CIN + ci0) * T_IN + t0;
    const int cl = tid >> 4, fc = tid & 15;
#pragma unroll
    for (int p = 0; p < 4; ++p) {
        float4 v = *reinterpret_cast<const float4*>(xb + (size_t)(cl + p * 16) * T_IN + fc * 4);
        *reinterpret_cast<float4*>(&tile[cl + p * 16][fc * 4]) = v;
    }
    __syncthreads();

    const int tl = tid >> 2, cg = (tid & 3) * 16;
    unsigned short tmp[16];
#pragma unroll
    for (int j = 0; j < 16; ++j) tmp[j] = f2bf(tile[cg + j][tl]);
    unsigned short* dst = xbf + ((size_t)b * T_IN + t0 + tl) * CIN + ci0 + cg;
    *reinterpret_cast<short8*>(dst)     = *reinterpret_cast<short8*>(tmp);
    *reinterpret_cast<short8*>(dst + 8) = *reinterpret_cast<short8*>(tmp + 8);
}

// ------- main kernel: 128x256 block, 4 waves of 128x64, 2 blocks/CU ---------
__global__ __launch_bounds__(256, 2)
void tdl_conv_w64(const unsigned short* __restrict__ xbf,
                  const unsigned short* __restrict__ wbf,
                  const float* __restrict__ bias,
                  float* __restrict__ out)
{
    // Wl: [5][128][32] bf16 = 40960 B ; Xl: [260][32] bf16 = 16640 B -> 57600 B
    __shared__ __align__(16) unsigned short Wl[KW_ * BM * BK];
    __shared__ __align__(16) unsigned short Xl[(BN2 + 4) * BK];

    const int tid  = threadIdx.x;
    const int lane = tid & 63;
    const int wn   = tid >> 6;   // 0..3 (t); every wave owns all 128 co rows

    // XCD-aware swizzle (grid 2048 % 8 == 0 -> bijective)
    const int bid     = blockIdx.x;
    const int logical = ((bid & 7) << 8) | (bid >> 3);
    const int co_t = logical & 3;
    const int t_t  = (logical >> 2) & 7;
    const int b    = logical >> 5;

    const int co0 = co_t * BM;
    const int t0  = t_t * BN2;

    const unsigned short* xb = xbf + (size_t)b * T_IN * CIN;

    floatx4 acc[8][4];
#pragma unroll
    for (int m = 0; m < 8; ++m)
#pragma unroll
        for (int n = 0; n < 4; ++n)
            acc[m][n] = (floatx4)(0.0f);

    const int arow = lane & 15;
    const int c0   = lane >> 4;                       // logical 16B chunk
    const int aswz = ((c0 ^ ((arow >> 1) & 3)) << 3); // W read swizzle (elems)

    for (int ci0 = 0; ci0 < CIN; ci0 += BK) {
        // stage W: 2560 16B-chunks over 256 threads = 10 each, linear LDS dest.
        // Source chunk pre-swizzled: c_g = c_l ^ ((co>>1)&3)  (rule #21)
#pragma unroll
        for (int it = 0; it < 10; ++it) {
            const int e  = tid + it * 256;
            const int kw = e >> 9;
            const int r  = e & 511;
            const int co = r >> 2;
            const int c8 = (((r & 3) ^ ((co >> 1) & 3)) << 3);
            gl_lds16(wbf + ((size_t)(kw * COUT + co0 + co)) * CIN + ci0 + c8,
                     &Wl[e * 8]);
        }
        // stage X: 1040 chunks = 4 uniform rounds + 16-thread tail
        // Source chunk pre-swizzled: c_g = c_l ^ ((t>>1)&3)
#pragma unroll
        for (int it = 0; it < 4; ++it) {
            const int e  = tid + it * 256;
            const int t  = e >> 2;
            const int c8 = (((e & 3) ^ ((t >> 1) & 3)) << 3);
            gl_lds16(xb + (size_t)(t0 + t) * CIN + ci0 + c8, &Xl[e * 8]);
        }
        if (tid < 16) {
            const int e  = 1024 + tid;
            const int t  = e >> 2;
            const int c8 = (((e & 3) ^ ((t >> 1) & 3)) << 3);
            int ts = t0 + t; if (ts > T_IN - 1) ts = T_IN - 1;  // feeds masked cols only
            gl_lds16(xb + (size_t)ts * CIN + ci0 + c8, &Xl[e * 8]);
        }
        __syncthreads();   // vmcnt(0) drain + barrier

#pragma unroll
        for (int kw = 0; kw < KW_; ++kw) {
            // X read swizzle: row = wn*64+n*16+arow+kw -> (row>>1)&3 = ((arow+kw)>>1)&3
            const int bswz = ((c0 ^ (((arow + kw) >> 1) & 3)) << 3);
            short8 af[8], bfr[4];
#pragma unroll
            for (int m = 0; m < 8; ++m)
                af[m] = *reinterpret_cast<const short8*>(
                    &Wl[(kw * BM + m * 16 + arow) * BK + aswz]);
#pragma unroll
            for (int n = 0; n < 4; ++n)
                bfr[n] = *reinterpret_cast<const short8*>(
                    &Xl[(wn * 64 + n * 16 + arow + kw) * BK + bswz]);
            __builtin_amdgcn_s_setprio(1);
#pragma unroll
            for (int m = 0; m < 8; ++m)
#pragma unroll
                for (int n = 0; n < 4; ++n)
                    acc[m][n] = __builtin_amdgcn_mfma_f32_16x16x32_bf16(
                        af[m], bfr[n], acc[m][n], 0, 0, 0);
            __builtin_amdgcn_s_setprio(0);
        }
        __syncthreads();   // all reads of Wl/Xl done before restage
    }

    // ---- epilogue: D layout col = lane&15 (t), row = (lane>>4)*4 + r (co)
    const int colb = wn * 64 + (lane & 15);
    const int rowb = (lane >> 4) * 4;
    float* outp = out + ((size_t)b * COUT + co0) * TOUT + t0;
#pragma unroll
    for (int m = 0; m < 8; ++m) {
        const int row0 = rowb + m * 16;
        float bv[4];
#pragma unroll
        for (int r = 0; r < 4; ++r) bv[r] = bias[co0 + row0 + r];
#pragma unroll
        for (int n = 0; n < 4; ++n) {
            const int col = colb + n * 16;
            if (t0 + col < TOUT) {
#pragma unroll
                for (int r = 0; r < 4; ++r)
                    outp[(size_t)(row0 + r) * TOUT + col] = acc[m][n][r] + bv[r];
            }
        }
    }
}

// ---------------- fallback (round-1 kernel, used if ws too small) -----------
#define PAD   40
__global__ __launch_bounds__(256, 2)
void tdl_conv_mfma(const float* __restrict__ x,
                   const float* __restrict__ w,
                   const float* __restrict__ bias,
                   float* __restrict__ out)
{
    __shared__ __align__(16) unsigned short Wlds[KW_][BM][PAD];
    __shared__ __align__(16) unsigned short Xlds[BM + 4][PAD];

    const int tid  = threadIdx.x;
    const int lane = tid & 63;
    const int wid  = tid >> 6;
    const int wm   = wid >> 1;
    const int wn   = wid & 1;

    const int bid  = blockIdx.x;
    const int co_t = bid & 3;
    const int t_t  = (bid >> 2) & 15;
    const int b    = bid >> 6;

    const int co0 = co_t * BM;
    const int t0  = t_t * BM;

    floatx4 acc[4][4];
#pragma unroll
    for (int m = 0; m < 4; ++m)
#pragma unroll
        for (int n = 0; n < 4; ++n)
            acc[m][n] = (floatx4)(0.0f);

    const float* xb = x + (size_t)b * CIN * T_IN;
    const int arow = lane & 15;
    const int k8   = (lane >> 4) * 8;

    for (int ci0 = 0; ci0 < CIN; ci0 += BK) {
        for (int e = tid; e < BK * 33; e += 256) {
            const int ci = e / 33;
            const int q  = e - ci * 33;
            const int tt = q * 4;
            const int tg = t0 + tt;
            float4 v = make_float4(0.f, 0.f, 0.f, 0.f);
            if (tg < T_IN)
                v = *reinterpret_cast<const float4*>(xb + (size_t)(ci0 + ci) * T_IN + tg);
            Xlds[tt + 0][ci] = f2bf(v.x);
            Xlds[tt + 1][ci] = f2bf(v.y);
            Xlds[tt + 2][ci] = f2bf(v.z);
            Xlds[tt + 3][ci] = f2bf(v.w);
        }
        for (int e = tid; e < BM * 40; e += 256) {
            const int co = e / 40;
            const int q  = e - co * 40;
            const float4 v = *reinterpret_cast<const float4*>(
                w + (size_t)(co0 + co) * (CIN * KW_) + ci0 * KW_ + q * 4);
            const int m0 = q * 4;
            Wlds[(m0    ) % 5][co][(m0    ) / 5] = f2bf(v.x);
            Wlds[(m0 + 1) % 5][co][(m0 + 1) / 5] = f2bf(v.y);
            Wlds[(m0 + 2) % 5][co][(m0 + 2) / 5] = f2bf(v.z);
            Wlds[(m0 + 3) % 5][co][(m0 + 3) / 5] = f2bf(v.w);
        }
        __syncthreads();
#pragma unroll
        for (int kw = 0; kw < KW_; ++kw) {
            short8 afrag[4], bfrag[4];
#pragma unroll
            for (int m = 0; m < 4; ++m)
                afrag[m] = *reinterpret_cast<const short8*>(
                    &Wlds[kw][wm * 64 + m * 16 + arow][k8]);
#pragma unroll
            for (int n = 0; n < 4; ++n)
                bfrag[n] = *reinterpret_cast<const short8*>(
                    &Xlds[wn * 64 + n * 16 + arow + kw][k8]);
#pragma unroll
            for (int m = 0; m < 4; ++m)
#pragma unroll
                for (int n = 0; n < 4; ++n)
                    acc[m][n] = __builtin_amdgcn_mfma_f32_16x16x32_bf16(
                        afrag[m], bfrag[n], acc[m][n], 0, 0, 0);
        }
        __syncthreads();
    }

    const int colb = wn * 64 + (lane & 15);
    const int rowb = wm * 64 + (lane >> 4) * 4;
    float* outp = out + ((size_t)b * COUT + co0) * TOUT + t0;
#pragma unroll
    for (int m = 0; m < 4; ++m) {
        const int row0 = rowb + m * 16;
        float bv[4];
#pragma unroll
        for (int r = 0; r < 4; ++r) bv[r] = bias[co0 + row0 + r];
#pragma unroll
        for (int n = 0; n < 4; ++n) {
            const int col = colb + n * 16;
            if (t0 + col < TOUT) {
#pragma unroll
                for (int r = 0; r < 4; ++r)
                    outp[(size_t)(row0 + r) * TOUT + col] = acc[m][n][r] + bv[r];
            }
        }
    }
}

extern "C" void kernel_launch(void* const* d_in, const int* in_sizes, int n_in,
                              void* d_out, int out_size, void* d_ws, size_t ws_size,
                              hipStream_t stream) {
    const float* x    = (const float*)d_in[0];
    const float* w    = (const float*)d_in[1];
    const float* bias = (const float*)d_in[2];
    float* out        = (float*)d_out;

    const size_t xbf_elems = (size_t)B_SZ * T_IN * CIN;
    const size_t wbf_elems = (size_t)KW_ * COUT * CIN;
    const size_t need = (xbf_elems + wbf_elems) * sizeof(unsigned short);

    if (ws_size >= need) {
        unsigned short* xbf = (unsigned short*)d_ws;
        unsigned short* wbf = xbf + xbf_elems;

        wconv_kernel<<<(COUT * CIN * KW_ + 255) / 256, 256, 0, stream>>>(w, wbf);
        dim3 tg(T_IN / 64, CIN / 64, B_SZ);
        xtrans_kernel<<<tg, 256, 0, stream>>>(x, xbf);
        // grid: 4 co-tiles * 8 t-tiles * 64 batches = 2048 blocks
        tdl_conv_w64<<<4 * 8 * B_SZ, 256, 0, stream>>>(xbf, wbf, bias, out);
    } else {
        tdl_conv_mfma<<<4 * 16 * B_SZ, 256, 0, stream>>>(x, w, bias, out);
    }
}